// Round 4
// baseline (2069.322 us; speedup 1.0000x reference)
//
#include <hip/hip_runtime.h>

#define HID 256
#define BATCH 512
#define MENC 16
#define HWIN 25
#define SALSZ 4096
#define BH (BATCH * HID)   // 131072

typedef __attribute__((ext_vector_type(8))) short bf16x8;
typedef __attribute__((ext_vector_type(4))) float f32x4;

__device__ __forceinline__ float sigmf(float x) { return 1.0f / (1.0f + __expf(-x)); }
__device__ __forceinline__ ushort f2bf(float f) {
    uint32_t u = __float_as_uint(f);
    return (ushort)((u + 0x7fffu + ((u >> 16) & 1u)) >> 16);   // RNE
}

#define GLOAD_LDS(gp, lp) \
    __builtin_amdgcn_global_load_lds((const __attribute__((address_space(1))) void*)(gp), \
                                     (__attribute__((address_space(3))) void*)(lp), 16, 0, 0)

// ---- device-scope grid barrier: one fresh pre-zeroed slot per sync point ----
__device__ __forceinline__ void gbar(unsigned int* slot, unsigned int nblk)
{
    __syncthreads();
    if (threadIdx.x == 0) {
        __threadfence();                 // release prior writes (device scope)
        atomicAdd(slot, 1u);
        while (__hip_atomic_load(slot, __ATOMIC_ACQUIRE, __HIP_MEMORY_SCOPE_AGENT) < nblk)
            __builtin_amdgcn_s_sleep(2);
    }
    __syncthreads();
}

// ---- shared LSTM-tile machinery (64 b x 256 k tiles, XOR-swizzled 16B units) ----
// H tile: rows = b-local. src rows at stride ld, source unit pre-swizzled.
__device__ __forceinline__ void stage_tile(const ushort* src, int ld, ushort* lds,
                                           int lane, int w)
{
    const int sub = lane >> 5, uu = lane & 31;
#pragma unroll
    for (int i = 0; i < 8; ++i) {
        const int row = i * 8 + w * 2 + sub;
        const int su  = uu ^ (row & 7);
        GLOAD_LDS(src + (size_t)row * ld + su * 8, lds + i * 2048 + w * 512);
    }
}
// W tile: LDS row vn = g*16+ul maps to global row g*256 + u0 + ul.
__device__ __forceinline__ void stage_wtile(const ushort* Wsrc, int ldw, int u0,
                                            ushort* lds, int lane, int w)
{
    const int sub = lane >> 5, uu = lane & 31;
#pragma unroll
    for (int i = 0; i < 8; ++i) {
        const int row = i * 8 + w * 2 + sub;
        const int su  = uu ^ (row & 7);
        const int gr  = (row >> 4) * HID + u0 + (row & 15);
        GLOAD_LDS(Wsrc + (size_t)gr * ldw + su * 8, lds + i * 2048 + w * 512);
    }
}
// 32 MFMA per wave: acc[g] += H(16b x 256k) * W(gate g, 16u x 256k)^T
__device__ __forceinline__ void mfma_tile(const ushort* Hs, const ushort* Ws,
                                          f32x4 acc[4], int lane, int w)
{
    const int fr = lane & 15, fq = lane >> 4;
#pragma unroll
    for (int ks = 0; ks < 8; ++ks) {
        const int ku = ks * 4 + fq;
        const int ar = w * 16 + fr;
        const bf16x8 af = *(const bf16x8*)(Hs + ar * 256 + (ku ^ (ar & 7)) * 8);
#pragma unroll
        for (int g = 0; g < 4; ++g) {
            const int vr = g * 16 + fr;
            const bf16x8 bf = *(const bf16x8*)(Ws + vr * 256 + (ku ^ (vr & 7)) * 8);
            acc[g] = __builtin_amdgcn_mfma_f32_16x16x32_bf16(af, bf, acc[g], 0, 0, 0);
        }
    }
}

// ---------------- fp32 -> bf16 ----------------
__global__ __launch_bounds__(256)
void cvt_f32_bf16(const float* __restrict__ in, ushort* __restrict__ out, int n4)
{
    const int i = blockIdx.x * 256 + threadIdx.x;
    if (i >= n4) return;
    const float4 v = *(const float4*)(in + (size_t)i * 4);
    *(ushort4*)(out + (size_t)i * 4) = make_ushort4(f2bf(v.x), f2bf(v.y), f2bf(v.z), f2bf(v.w));
}

// ---------------- big bf16 MFMA GEMM: C[M,N] = A[M,K] @ W[N,K]^T (m97, no swizzle) ----------------
__global__ __launch_bounds__(256)
void gemm_mfma_bt(const ushort* __restrict__ A, const ushort* __restrict__ W,
                  float* __restrict__ C, int M, int N, int K,
                  int lda, int ldw, int ldc)
{
    __shared__ ushort As[128 * 32];
    __shared__ ushort Bs[128 * 32];
    const int t    = threadIdx.x;
    const int lane = t & 63, wid = t >> 6;
    const int m0 = blockIdx.y * 128, n0 = blockIdx.x * 128;
    const int wr = wid >> 1, wc = wid & 1;

    f32x4 acc[4][4] = {};

    const int sr = wid * 16 + (lane >> 2);
    const int sk = (lane & 3) * 8;
    const ushort* Ag = A + (size_t)(m0 + sr) * lda + sk;
    const ushort* Wg = W + (size_t)(n0 + sr) * ldw + sk;
    ushort* Al = As + wid * 512;
    ushort* Bl = Bs + wid * 512;

    const int fr = lane & 15;
    const int fk = (lane >> 4) * 8;

    for (int k0 = 0; k0 < K; k0 += 32) {
        GLOAD_LDS(Ag,                    Al);
        GLOAD_LDS(Ag + (size_t)64 * lda, Al + 2048);
        GLOAD_LDS(Wg,                    Bl);
        GLOAD_LDS(Wg + (size_t)64 * ldw, Bl + 2048);
        Ag += 32; Wg += 32;
        __syncthreads();

        bf16x8 af[4], bfr[4];
#pragma unroll
        for (int m = 0; m < 4; ++m)
            af[m] = *(const bf16x8*)(As + (wr * 64 + m * 16 + fr) * 32 + fk);
#pragma unroll
        for (int n = 0; n < 4; ++n)
            bfr[n] = *(const bf16x8*)(Bs + (wc * 64 + n * 16 + fr) * 32 + fk);
#pragma unroll
        for (int m = 0; m < 4; ++m)
#pragma unroll
            for (int n = 0; n < 4; ++n)
                acc[m][n] = __builtin_amdgcn_mfma_f32_16x16x32_bf16(af[m], bfr[n], acc[m][n], 0, 0, 0);
        __syncthreads();
    }

    const int cl = lane & 15, ch = lane >> 4;
#pragma unroll
    for (int m = 0; m < 4; ++m)
#pragma unroll
        for (int n = 0; n < 4; ++n)
#pragma unroll
            for (int r = 0; r < 4; ++r)
                C[(size_t)(m0 + wr * 64 + m * 16 + ch * 4 + r) * ldc
                  + n0 + wc * 64 + n * 16 + cl] = acc[m][n][r];
}

// ---------------- fp32 tiled GEMM (GBIAS one-off) ----------------
__global__ __launch_bounds__(256)
void gemm_tn(const float* __restrict__ A, const float* __restrict__ W,
             const float* __restrict__ b1, const float* __restrict__ b2,
             float* __restrict__ C,
             int M, int N, int K, int lda, int ldw, int ldc)
{
    __shared__ float AsT[16][68];
    __shared__ float WsT[16][68];
    const int t  = threadIdx.x;
    const int tx = t & 15, ty = t >> 4;
    const int m0 = blockIdx.y * 64, n0 = blockIdx.x * 64;
    const int lr = t >> 2;
    const int c4 = t & 3;

    float acc[4][4];
#pragma unroll
    for (int i = 0; i < 4; ++i)
#pragma unroll
        for (int j = 0; j < 4; ++j) acc[i][j] = 0.0f;

    for (int k0 = 0; k0 < K; k0 += 16) {
        float a[4], w[4];
        const int kb = k0 + c4 * 4;
        if (kb + 3 < K) {
            const float4 av = *(const float4*)(A + (size_t)(m0 + lr) * lda + kb);
            a[0] = av.x; a[1] = av.y; a[2] = av.z; a[3] = av.w;
            const float4 wv = *(const float4*)(W + (size_t)(n0 + lr) * ldw + kb);
            w[0] = wv.x; w[1] = wv.y; w[2] = wv.z; w[3] = wv.w;
        } else {
#pragma unroll
            for (int k = 0; k < 4; ++k) {
                a[k] = (kb + k < K) ? A[(size_t)(m0 + lr) * lda + kb + k] : 0.0f;
                w[k] = (kb + k < K) ? W[(size_t)(n0 + lr) * ldw + kb + k] : 0.0f;
            }
        }
        __syncthreads();
#pragma unroll
        for (int k = 0; k < 4; ++k) {
            AsT[c4 * 4 + k][lr] = a[k];
            WsT[c4 * 4 + k][lr] = w[k];
        }
        __syncthreads();
#pragma unroll
        for (int kk = 0; kk < 16; ++kk) {
            const float4 av = *(const float4*)&AsT[kk][ty * 4];
            const float4 wv = *(const float4*)&WsT[kk][tx * 4];
            acc[0][0] += av.x * wv.x; acc[0][1] += av.x * wv.y; acc[0][2] += av.x * wv.z; acc[0][3] += av.x * wv.w;
            acc[1][0] += av.y * wv.x; acc[1][1] += av.y * wv.y; acc[1][2] += av.y * wv.z; acc[1][3] += av.y * wv.w;
            acc[2][0] += av.z * wv.x; acc[2][1] += av.z * wv.y; acc[2][2] += av.z * wv.z; acc[2][3] += av.z * wv.w;
            acc[3][0] += av.w * wv.x; acc[3][1] += av.w * wv.y; acc[3][2] += av.w * wv.z; acc[3][3] += av.w * wv.w;
        }
    }

#pragma unroll
    for (int i = 0; i < 4; ++i) {
        const int m = m0 + ty * 4 + i;
#pragma unroll
        for (int j = 0; j < 4; ++j) {
            const int n = n0 + tx * 4 + j;
            float v = acc[i][j];
            if (b1) v += b1[n];
            if (b2) v += b2[n];
            C[(size_t)m * ldc + n] = v;
        }
    }
}

// ---------------- persistent encoder: se + pe chains, 16 steps ----------------
struct EncArgs {
    const ushort *WHse, *WHpe;
    const float  *xg_se;     // [512*16][1024], rows (b,t)
    const float  *enc_pos;   // [512][16][3]
    const float  *se_b1, *se_b2, *pe_b1, *pe_b2;
    const float  *pe_Wih;    // [1024][3]
    ushort       *conc;      // [16][512][512] bf16 (se cols 0:256, pe 256:512)
    float        *SE_C, *PE_C;
    unsigned int *bar;       // 16 slots
};

__global__ __launch_bounds__(256)
void enc_chain(EncArgs A)
{
    __shared__ ushort Hs[64 * 256], Ws[64 * 256];
    const int tid = threadIdx.x, lane = tid & 63, w = tid >> 6;
    const int role = blockIdx.x >> 7;           // 0 = se, 1 = pe
    const int b7 = blockIdx.x & 127;
    const int b0 = (b7 & 7) * 64, u0 = (b7 >> 3) * 16;
    const int fr = lane & 15, fq = lane >> 4;
    const int u = u0 + fr;
    const int coff = role ? 256 : 0;

    stage_wtile(role ? A.WHpe : A.WHse, HID, u0, Ws, lane, w);

    const float* b1 = role ? A.pe_b1 : A.se_b1;
    const float* b2 = role ? A.pe_b2 : A.se_b2;
    float bias[4], wxs[4][3];
#pragma unroll
    for (int g = 0; g < 4; ++g) {
        bias[g] = b1[g * HID + u] + b2[g * HID + u];
        wxs[g][0] = wxs[g][1] = wxs[g][2] = 0.0f;
        if (role) {
            wxs[g][0] = A.pe_Wih[(g * HID + u) * 3 + 0];
            wxs[g][1] = A.pe_Wih[(g * HID + u) * 3 + 1];
            wxs[g][2] = A.pe_Wih[(g * HID + u) * 3 + 2];
        }
    }
    float c[4] = {0.f, 0.f, 0.f, 0.f};

    for (int t = 0; t < MENC; ++t) {
        f32x4 acc[4] = {};
        if (t > 0) {
            stage_tile(A.conc + ((size_t)(t - 1) * 512 + b0) * 512 + coff, 512, Hs, lane, w);
            __syncthreads();
            mfma_tile(Hs, Ws, acc, lane, w);
        }
#pragma unroll
        for (int r = 0; r < 4; ++r) {
            const int b = b0 + w * 16 + fq * 4 + r;
            float x0 = 0.f, x1 = 0.f, x2 = 0.f;
            if (role) {
                const float* xp = A.enc_pos + ((size_t)b * MENC + t) * 3;
                x0 = xp[0]; x1 = xp[1]; x2 = xp[2];
            }
            float gv[4];
#pragma unroll
            for (int g = 0; g < 4; ++g) {
                float v = acc[g][r] + bias[g];
                if (role) v += x0 * wxs[g][0] + x1 * wxs[g][1] + x2 * wxs[g][2];
                else      v += A.xg_se[((size_t)b * MENC + t) * 1024 + g * HID + u];
                gv[g] = v;
            }
            const float cn = sigmf(gv[1]) * c[r] + sigmf(gv[0]) * tanhf(gv[2]);
            const float hn = sigmf(gv[3]) * tanhf(cn);
            c[r] = cn;
            A.conc[((size_t)t * 512 + b) * 512 + coff + u] = f2bf(hn);
            if (t == MENC - 1) (role ? A.PE_C : A.SE_C)[(size_t)b * HID + u] = cn;
        }
        gbar(A.bar + t, 256);
    }
}

// ---------------- persistent mid: sd (25 steps) + fe (16 steps) ----------------
struct MidArgs {
    const ushort *WHsd, *WHfe;
    const float  *xg_sd;     // rows (b*25+t)
    const float  *xg_fe;     // rows (t*512+b)
    const float  *sd_b1, *sd_b2, *fe_b1, *fe_b2;
    const ushort *conc;      // sd t=0 h-in = conc[15][b][0:256]
    const float  *SE_C;
    ushort       *SDB;       // [25][512][256]
    ushort       *FEB;       // [2][512][256]
    float        *FEH, *FE_C;
    unsigned int *bar;       // 25 slots
};

__global__ __launch_bounds__(256)
void mid_chain(MidArgs A)
{
    __shared__ ushort Hs[64 * 256], Ws[64 * 256];
    const int tid = threadIdx.x, lane = tid & 63, w = tid >> 6;
    const int role = blockIdx.x >> 7;           // 0 = sd, 1 = fe
    const int b7 = blockIdx.x & 127;
    const int b0 = (b7 & 7) * 64, u0 = (b7 >> 3) * 16;
    const int fr = lane & 15, fq = lane >> 4;
    const int u = u0 + fr;

    stage_wtile(role ? A.WHfe : A.WHsd, HID, u0, Ws, lane, w);

    const float* b1 = role ? A.fe_b1 : A.sd_b1;
    const float* b2 = role ? A.fe_b2 : A.sd_b2;
    float bias[4];
#pragma unroll
    for (int g = 0; g < 4; ++g) bias[g] = b1[g * HID + u] + b2[g * HID + u];

    float c[4];
#pragma unroll
    for (int r = 0; r < 4; ++r) {
        const int b = b0 + w * 16 + fq * 4 + r;
        c[r] = role ? 0.0f : A.SE_C[(size_t)b * HID + u];
    }

    for (int t = 0; t < HWIN; ++t) {
        if (role == 0 || t < MENC) {
            f32x4 acc[4] = {};
            const bool doH = !(role == 1 && t == 0);
            if (doH) {
                const ushort* hsrc; int ldh;
                if (role == 0) {
                    if (t == 0) { hsrc = A.conc + ((size_t)15 * 512 + b0) * 512; ldh = 512; }
                    else        { hsrc = A.SDB + ((size_t)(t - 1) * 512 + b0) * HID; ldh = HID; }
                } else {
                    hsrc = A.FEB + ((size_t)((t - 1) & 1) * BATCH + b0) * HID; ldh = HID;
                }
                stage_tile(hsrc, ldh, Hs, lane, w);
                __syncthreads();
                mfma_tile(Hs, Ws, acc, lane, w);
            }
#pragma unroll
            for (int r = 0; r < 4; ++r) {
                const int b = b0 + w * 16 + fq * 4 + r;
                float gv[4];
#pragma unroll
                for (int g = 0; g < 4; ++g) {
                    float v = acc[g][r] + bias[g];
                    if (role) v += A.xg_fe[((size_t)t * 512 + b) * 1024 + g * HID + u];
                    else      v += A.xg_sd[((size_t)b * HWIN + t) * 1024 + g * HID + u];
                    gv[g] = v;
                }
                const float cn = sigmf(gv[1]) * c[r] + sigmf(gv[0]) * tanhf(gv[2]);
                const float hn = sigmf(gv[3]) * tanhf(cn);
                c[r] = cn;
                if (role == 0) {
                    A.SDB[((size_t)t * 512 + b) * HID + u] = f2bf(hn);
                } else {
                    A.FEB[((size_t)(t & 1) * BATCH + b) * HID + u] = f2bf(hn);
                    if (t == MENC - 1) {
                        A.FEH[(size_t)b * HID + u] = hn;
                        A.FE_C[(size_t)b * HID + u] = cn;
                    }
                }
            }
        }
        gbar(A.bar + t, 256);
    }
}

// ---------------- persistent decoder: pd + fd + tail, 25 steps ----------------
struct DecArgs {
    const ushort *WHpd;      // [1024][256]
    const ushort *WFDh;      // fd_Wih cols 256:512 view: base = WFD+256, ld 512
    const ushort *peF;       // conc[15] + 256, ld 512
    const float  *PE_C, *FE_C, *GBIAS;
    const float  *xh2;       // [25*512][1024], rows (t,b)
    const float  *pd_b1, *pd_b2, *pd_Wih;
    const float  *G, *c3, *dec_pos;
    ushort       *H1;        // [2][512][256]
    float        *DELTA;     // [25][512][3], pre-zeroed
    float        *out;       // [512][25][3]
    unsigned int *bar;       // 50 slots
};

__global__ __launch_bounds__(256)
void dec_chain(DecArgs A)
{
    __shared__ ushort Wpd[64 * 256], Wfd[64 * 256], Hs[64 * 256];
    __shared__ float pred_lds[192];
    const int tid = threadIdx.x, lane = tid & 63, w = tid >> 6;
    const int b0 = (blockIdx.x & 7) * 64, u0 = (blockIdx.x >> 3) * 16;
    const int fr = lane & 15, fq = lane >> 4;
    const int u = u0 + fr;

    stage_wtile(A.WHpd, HID, u0, Wpd, lane, w);
    stage_wtile(A.WFDh, 512, u0, Wfd, lane, w);

    float pdb[4], wxs[4][3], gb[4][4], cf[4], c1[4], Gu[3];
#pragma unroll
    for (int g = 0; g < 4; ++g) {
        pdb[g] = A.pd_b1[g * HID + u] + A.pd_b2[g * HID + u];
        wxs[g][0] = A.pd_Wih[(g * HID + u) * 3 + 0];
        wxs[g][1] = A.pd_Wih[(g * HID + u) * 3 + 1];
        wxs[g][2] = A.pd_Wih[(g * HID + u) * 3 + 2];
    }
#pragma unroll
    for (int r = 0; r < 4; ++r) {
        const int b = b0 + w * 16 + fq * 4 + r;
        c1[r] = A.PE_C[(size_t)b * HID + u];
        cf[r] = A.FE_C[(size_t)b * HID + u];
#pragma unroll
        for (int g = 0; g < 4; ++g) gb[r][g] = A.GBIAS[(size_t)b * 1024 + g * HID + u];
    }
    Gu[0] = A.G[0 * HID + u]; Gu[1] = A.G[1 * HID + u]; Gu[2] = A.G[2 * HID + u];
    const float c3r = (tid < 192) ? A.c3[tid % 3] : 0.0f;
    if (tid < 192) pred_lds[tid] = A.dec_pos[(size_t)(b0 + tid / 3) * 3 + tid % 3];
    __syncthreads();

    for (int t = 0; t < HWIN; ++t) {
        // ---- phase A: pd cell ----
        {
            f32x4 acc[4] = {};
            const ushort* hsrc; int ldh;
            if (t == 0) { hsrc = A.peF + (size_t)b0 * 512; ldh = 512; }
            else        { hsrc = A.H1 + ((size_t)((t - 1) & 1) * BATCH + b0) * HID; ldh = HID; }
            stage_tile(hsrc, ldh, Hs, lane, w);
            __syncthreads();
            mfma_tile(Hs, Wpd, acc, lane, w);
#pragma unroll
            for (int r = 0; r < 4; ++r) {
                const int bl = w * 16 + fq * 4 + r, b = b0 + bl;
                const float x0 = pred_lds[bl * 3 + 0];
                const float x1 = pred_lds[bl * 3 + 1];
                const float x2 = pred_lds[bl * 3 + 2];
                float gv[4];
#pragma unroll
                for (int g = 0; g < 4; ++g)
                    gv[g] = acc[g][r] + pdb[g] + x0 * wxs[g][0] + x1 * wxs[g][1] + x2 * wxs[g][2];
                const float cn = sigmf(gv[1]) * c1[r] + sigmf(gv[0]) * tanhf(gv[2]);
                const float hn = sigmf(gv[3]) * tanhf(cn);
                c1[r] = cn;
                A.H1[((size_t)(t & 1) * BATCH + b) * HID + u] = f2bf(hn);
            }
        }
        gbar(A.bar + 2 * t, 128);
        // ---- phase B: fd cell + tail partials ----
        {
            f32x4 acc[4] = {};
            stage_tile(A.H1 + ((size_t)(t & 1) * BATCH + b0) * HID, HID, Hs, lane, w);
            __syncthreads();
            mfma_tile(Hs, Wfd, acc, lane, w);
#pragma unroll
            for (int r = 0; r < 4; ++r) {
                const int b = b0 + w * 16 + fq * 4 + r;
                float gv[4];
#pragma unroll
                for (int g = 0; g < 4; ++g)
                    gv[g] = acc[g][r] + A.xh2[((size_t)t * 512 + b) * 1024 + g * HID + u] + gb[r][g];
                const float cn = sigmf(gv[1]) * cf[r] + sigmf(gv[0]) * tanhf(gv[2]);
                const float hn = sigmf(gv[3]) * tanhf(cn);
                float p0 = hn * Gu[0], p1 = hn * Gu[1], p2 = hn * Gu[2];
#pragma unroll
                for (int s = 1; s < 16; s <<= 1) {
                    p0 += __shfl_xor(p0, s);
                    p1 += __shfl_xor(p1, s);
                    p2 += __shfl_xor(p2, s);
                }
                if (fr == 0) {
                    float* d = A.DELTA + ((size_t)t * 512 + b) * 3;
                    atomicAdd(d + 0, p0); atomicAdd(d + 1, p1); atomicAdd(d + 2, p2);
                }
            }
        }
        gbar(A.bar + 2 * t + 1, 128);
        // ---- pred update + out ----
        if (tid < 192) {
            pred_lds[tid] += A.DELTA[((size_t)t * 512 + b0 + tid / 3) * 3 + tid % 3] + c3r;
            if (u0 == 0)
                A.out[((size_t)(b0 + tid / 3) * HWIN + t) * 3 + tid % 3] = pred_lds[tid];
        }
        __syncthreads();
    }
}

// ---------------- G = out_W @ f2_W, c3 = out_b + out_W @ f2_b ----------------
__global__ __launch_bounds__(256)
void precompute_G(const float* __restrict__ f2W, const float* __restrict__ f2b,
                  const float* __restrict__ outW, const float* __restrict__ outb,
                  float* __restrict__ G, float* __restrict__ c3)
{
    const int k = threadIdx.x;
    float g0 = 0.f, g1 = 0.f, g2 = 0.f;
    for (int n = 0; n < HID; ++n) {
        const float w = f2W[n * HID + k];
        g0 += outW[n] * w;
        g1 += outW[HID + n] * w;
        g2 += outW[2 * HID + n] * w;
    }
    G[k] = g0; G[HID + k] = g1; G[2 * HID + k] = g2;
    if (k < 3) {
        float s = outb[k];
        for (int n = 0; n < HID; ++n) s += outW[k * HID + n] * f2b[n];
        c3[k] = s;
    }
}

extern "C" void kernel_launch(void* const* d_in, const int* in_sizes, int n_in,
                              void* d_out, int out_size, void* d_ws, size_t ws_size,
                              hipStream_t stream)
{
    (void)in_sizes; (void)n_in; (void)out_size; (void)ws_size;
    const float* enc_pos = (const float*)d_in[0];
    const float* enc_sal = (const float*)d_in[1];
    const float* dec_pos = (const float*)d_in[2];
    const float* dec_sal = (const float*)d_in[3];
    const float *pe_Wih = (const float*)d_in[4],  *pe_Whh = (const float*)d_in[5],
                *pe_bih = (const float*)d_in[6],  *pe_bhh = (const float*)d_in[7];
    const float *se_Wih = (const float*)d_in[8],  *se_Whh = (const float*)d_in[9],
                *se_bih = (const float*)d_in[10], *se_bhh = (const float*)d_in[11];
    const float *fe_Wih = (const float*)d_in[12], *fe_Whh = (const float*)d_in[13],
                *fe_bih = (const float*)d_in[14], *fe_bhh = (const float*)d_in[15];
    const float *pd_Wih = (const float*)d_in[16], *pd_Whh = (const float*)d_in[17],
                *pd_bih = (const float*)d_in[18], *pd_bhh = (const float*)d_in[19];
    const float *sd_Wih = (const float*)d_in[20], *sd_Whh = (const float*)d_in[21],
                *sd_bih = (const float*)d_in[22], *sd_bhh = (const float*)d_in[23];
    const float *fd_Wih = (const float*)d_in[24], *fd_Whh = (const float*)d_in[25],
                *fd_bih = (const float*)d_in[26], *fd_bhh = (const float*)d_in[27];
    const float *f2_W = (const float*)d_in[28], *f2_b = (const float*)d_in[29];
    const float *out_W = (const float*)d_in[30], *out_b = (const float*)d_in[31];
    float* out = (float*)d_out;
    float* ws  = (float*)d_ws;

    // ---- workspace (float units) ----
    size_t off = 0;
    float* XG_SE = ws + off; off += (size_t)8192 * 1024;    // se x-proj, rows (b,t)
    float* XG_FE = ws + off; off += (size_t)8192 * 1024;    // fe x-proj, rows (t,b)
    float* BIG   = ws + off; off += (size_t)12800 * 1024;   // sd x-proj, rows (b,t)
    float* BIG2  = ws + off; off += (size_t)12800 * 1024;   // fd Xh2, rows (t,b)
    float* GBIAS = ws + off; off += (size_t)BATCH * 1024;
    float* PE_C  = ws + off; off += BH;
    float* SE_C  = ws + off; off += BH;
    float* FE_C  = ws + off; off += BH;
    float* FEH   = ws + off; off += BH;
    float* Gm    = ws + off; off += 1024;
    float* C3    = ws + off; off += 8;
    float* DELTA = ws + off; off += (size_t)HWIN * BATCH * 3 + 64;
    unsigned int* BAR = (unsigned int*)(ws + off); off += 128;
    ushort* ABUF = (ushort*)(ws + off); off += ((size_t)12800 * 4096) / 2;
    ushort* WSE  = (ushort*)(ws + off); off += ((size_t)1024 * 4096) / 2;
    ushort* WSD  = (ushort*)(ws + off); off += ((size_t)1024 * 4096) / 2;
    ushort* WFE  = (ushort*)(ws + off); off += ((size_t)1024 * 512) / 2;
    ushort* WFD  = (ushort*)(ws + off); off += ((size_t)1024 * 512) / 2;
    ushort* WHpe = (ushort*)(ws + off); off += ((size_t)1024 * 256) / 2;
    ushort* WHse = (ushort*)(ws + off); off += ((size_t)1024 * 256) / 2;
    ushort* WHfe = (ushort*)(ws + off); off += ((size_t)1024 * 256) / 2;
    ushort* WHsd = (ushort*)(ws + off); off += ((size_t)1024 * 256) / 2;
    ushort* WHpd = (ushort*)(ws + off); off += ((size_t)1024 * 256) / 2;
    ushort* CONC = (ushort*)(ws + off); off += ((size_t)MENC * 512 * 512) / 2;  // [t][b][512]
    ushort* SDB  = (ushort*)(ws + off); off += ((size_t)HWIN * BH) / 2;         // [t][b][256]
    ushort* FEB  = (ushort*)(ws + off); off += (size_t)BH;                      // [2][512][256]
    ushort* H1   = (ushort*)(ws + off); off += (size_t)BH;                      // [2][512][256]

    hipMemsetAsync(DELTA, 0, (size_t)HWIN * BATCH * 3 * 4, stream);
    hipMemsetAsync(BAR, 0, 128 * 4, stream);

    auto cvt = [&](const float* in, ushort* outp, size_t n) {
        const int n4 = (int)(n / 4);
        cvt_f32_bf16<<<(n4 + 255) / 256, 256, 0, stream>>>(in, outp, n4);
    };
    auto mgemm = [&](const ushort* A, const ushort* W, float* C,
                     int M, int N, int K, int lda, int ldw, int ldc) {
        gemm_mfma_bt<<<dim3(N / 128, M / 128), 256, 0, stream>>>(A, W, C, M, N, K, lda, ldw, ldc);
    };

    // ---- one-time conversions / precomputes ----
    cvt(se_Wih, WSE, (size_t)1024 * SALSZ);
    cvt(sd_Wih, WSD, (size_t)1024 * SALSZ);
    cvt(fe_Wih, WFE, (size_t)1024 * 512);
    cvt(fd_Wih, WFD, (size_t)1024 * 512);
    cvt(pe_Whh, WHpe, (size_t)1024 * 256);
    cvt(se_Whh, WHse, (size_t)1024 * 256);
    cvt(fe_Whh, WHfe, (size_t)1024 * 256);
    cvt(sd_Whh, WHsd, (size_t)1024 * 256);
    cvt(pd_Whh, WHpd, (size_t)1024 * 256);
    cvt(enc_sal, ABUF, (size_t)8192 * SALSZ);
    precompute_G<<<1, 256, 0, stream>>>(f2_W, f2_b, out_W, out_b, Gm, C3);

    // ---- se x-projection ----
    mgemm(ABUF, WSE, XG_SE, 8192, 1024, SALSZ, SALSZ, SALSZ, 1024);

    // ---- persistent encoder (se + pe) ----
    {
        EncArgs a;
        a.WHse = WHse; a.WHpe = WHpe; a.xg_se = XG_SE; a.enc_pos = enc_pos;
        a.se_b1 = se_bih; a.se_b2 = se_bhh; a.pe_b1 = pe_bih; a.pe_b2 = pe_bhh;
        a.pe_Wih = pe_Wih; a.conc = CONC; a.SE_C = SE_C; a.PE_C = PE_C;
        a.bar = BAR;
        enc_chain<<<256, 256, 0, stream>>>(a);
    }

    // ---- fe x-proj (rows t,b) + sd x-proj ----
    mgemm(CONC, WFE, XG_FE, 8192, 1024, 512, 512, 512, 1024);
    cvt(dec_sal, ABUF, (size_t)12800 * SALSZ);
    mgemm(ABUF, WSD, BIG, 12800, 1024, SALSZ, SALSZ, SALSZ, 1024);

    // ---- persistent mid (sd + fe) ----
    {
        MidArgs a;
        a.WHsd = WHsd; a.WHfe = WHfe; a.xg_sd = BIG; a.xg_fe = XG_FE;
        a.sd_b1 = sd_bih; a.sd_b2 = sd_bhh; a.fe_b1 = fe_bih; a.fe_b2 = fe_bhh;
        a.conc = CONC; a.SE_C = SE_C; a.SDB = SDB; a.FEB = FEB;
        a.FEH = FEH; a.FE_C = FE_C; a.bar = BAR + 16;
        mid_chain<<<256, 256, 0, stream>>>(a);
    }

    // ---- fd precomputations ----
    mgemm(SDB, WFD, BIG2, 12800, 1024, HID, HID, 512, 1024);   // Xh2, rows (t,b)
    gemm_tn<<<dim3(16, 8), 256, 0, stream>>>(FEH, fd_Whh, fd_bih, fd_bhh, GBIAS,
                                             BATCH, 1024, HID, HID, HID, 1024);

    // ---- persistent decoder (pd + fd + tail) ----
    {
        DecArgs a;
        a.WHpd = WHpd; a.WFDh = WFD + 256;
        a.peF = CONC + ((size_t)15 * 512) * 512 + 256;
        a.PE_C = PE_C; a.FE_C = FE_C; a.GBIAS = GBIAS; a.xh2 = BIG2;
        a.pd_b1 = pd_bih; a.pd_b2 = pd_bhh; a.pd_Wih = pd_Wih;
        a.G = Gm; a.c3 = C3; a.dec_pos = dec_pos;
        a.H1 = H1; a.DELTA = DELTA; a.out = out; a.bar = BAR + 41;
        dec_chain<<<128, 256, 0, stream>>>(a);
    }
}

// Round 5
// 1534.386 us; speedup vs baseline: 1.3486x; 1.3486x over previous
//
#include <hip/hip_runtime.h>

#define HID 256
#define BATCH 512
#define MENC 16
#define HWIN 25
#define SALSZ 4096
#define BH (BATCH * HID)   // 131072

typedef __attribute__((ext_vector_type(8))) short bf16x8;
typedef __attribute__((ext_vector_type(4))) float f32x4;

__device__ __forceinline__ float sigmf(float x) { return 1.0f / (1.0f + __expf(-x)); }
__device__ __forceinline__ ushort f2bf(float f) {
    uint32_t u = __float_as_uint(f);
    return (ushort)((u + 0x7fffu + ((u >> 16) & 1u)) >> 16);   // RNE
}

#define GLOAD_LDS(gp, lp) \
    __builtin_amdgcn_global_load_lds((const __attribute__((address_space(1))) void*)(gp), \
                                     (__attribute__((address_space(3))) void*)(lp), 16, 0, 0)

// ---- group-local device barrier: RELAXED spin (no per-poll invalidate), ----
// ---- single agent-acquire fence after the count is reached.              ----
__device__ __forceinline__ void gbar(unsigned int* slot, unsigned int nblk)
{
    __syncthreads();
    if (threadIdx.x == 0) {
        __threadfence();                          // release prior writes (agent)
        atomicAdd(slot, 1u);
        while (__hip_atomic_load(slot, __ATOMIC_RELAXED, __HIP_MEMORY_SCOPE_AGENT) < nblk)
            __builtin_amdgcn_s_sleep(2);
        __builtin_amdgcn_fence(__ATOMIC_ACQUIRE, "agent");   // one invalidate
    }
    __syncthreads();
}

// ---- shared LSTM-tile machinery (64 b x 256 k tiles, XOR-swizzled 16B units) ----
__device__ __forceinline__ void stage_tile(const ushort* src, int ld, ushort* lds,
                                           int lane, int w)
{
    const int sub = lane >> 5, uu = lane & 31;
#pragma unroll
    for (int i = 0; i < 8; ++i) {
        const int row = i * 8 + w * 2 + sub;
        const int su  = uu ^ (row & 7);
        GLOAD_LDS(src + (size_t)row * ld + su * 8, lds + i * 2048 + w * 512);
    }
}
__device__ __forceinline__ void stage_wtile(const ushort* Wsrc, int ldw, int u0,
                                            ushort* lds, int lane, int w)
{
    const int sub = lane >> 5, uu = lane & 31;
#pragma unroll
    for (int i = 0; i < 8; ++i) {
        const int row = i * 8 + w * 2 + sub;
        const int su  = uu ^ (row & 7);
        const int gr  = (row >> 4) * HID + u0 + (row & 15);
        GLOAD_LDS(Wsrc + (size_t)gr * ldw + su * 8, lds + i * 2048 + w * 512);
    }
}
__device__ __forceinline__ void mfma_tile(const ushort* Hs, const ushort* Ws,
                                          f32x4 acc[4], int lane, int w)
{
    const int fr = lane & 15, fq = lane >> 4;
#pragma unroll
    for (int ks = 0; ks < 8; ++ks) {
        const int ku = ks * 4 + fq;
        const int ar = w * 16 + fr;
        const bf16x8 af = *(const bf16x8*)(Hs + ar * 256 + (ku ^ (ar & 7)) * 8);
#pragma unroll
        for (int g = 0; g < 4; ++g) {
            const int vr = g * 16 + fr;
            const bf16x8 bf = *(const bf16x8*)(Ws + vr * 256 + (ku ^ (vr & 7)) * 8);
            acc[g] = __builtin_amdgcn_mfma_f32_16x16x32_bf16(af, bf, acc[g], 0, 0, 0);
        }
    }
}

// ---------------- fp32 -> bf16 ----------------
__global__ __launch_bounds__(256)
void cvt_f32_bf16(const float* __restrict__ in, ushort* __restrict__ out, int n4)
{
    const int i = blockIdx.x * 256 + threadIdx.x;
    if (i >= n4) return;
    const float4 v = *(const float4*)(in + (size_t)i * 4);
    *(ushort4*)(out + (size_t)i * 4) = make_ushort4(f2bf(v.x), f2bf(v.y), f2bf(v.z), f2bf(v.w));
}

// ---------------- big bf16 MFMA GEMM: C[M,N] = A[M,K] @ W[N,K]^T (m97) ----------------
__global__ __launch_bounds__(256)
void gemm_mfma_bt(const ushort* __restrict__ A, const ushort* __restrict__ W,
                  float* __restrict__ C, int M, int N, int K,
                  int lda, int ldw, int ldc)
{
    __shared__ ushort As[128 * 32];
    __shared__ ushort Bs[128 * 32];
    const int t    = threadIdx.x;
    const int lane = t & 63, wid = t >> 6;
    const int m0 = blockIdx.y * 128, n0 = blockIdx.x * 128;
    const int wr = wid >> 1, wc = wid & 1;

    f32x4 acc[4][4] = {};

    const int sr = wid * 16 + (lane >> 2);
    const int sk = (lane & 3) * 8;
    const ushort* Ag = A + (size_t)(m0 + sr) * lda + sk;
    const ushort* Wg = W + (size_t)(n0 + sr) * ldw + sk;
    ushort* Al = As + wid * 512;
    ushort* Bl = Bs + wid * 512;

    const int fr = lane & 15;
    const int fk = (lane >> 4) * 8;

    for (int k0 = 0; k0 < K; k0 += 32) {
        GLOAD_LDS(Ag,                    Al);
        GLOAD_LDS(Ag + (size_t)64 * lda, Al + 2048);
        GLOAD_LDS(Wg,                    Bl);
        GLOAD_LDS(Wg + (size_t)64 * ldw, Bl + 2048);
        Ag += 32; Wg += 32;
        __syncthreads();

        bf16x8 af[4], bfr[4];
#pragma unroll
        for (int m = 0; m < 4; ++m)
            af[m] = *(const bf16x8*)(As + (wr * 64 + m * 16 + fr) * 32 + fk);
#pragma unroll
        for (int n = 0; n < 4; ++n)
            bfr[n] = *(const bf16x8*)(Bs + (wc * 64 + n * 16 + fr) * 32 + fk);
#pragma unroll
        for (int m = 0; m < 4; ++m)
#pragma unroll
            for (int n = 0; n < 4; ++n)
                acc[m][n] = __builtin_amdgcn_mfma_f32_16x16x32_bf16(af[m], bfr[n], acc[m][n], 0, 0, 0);
        __syncthreads();
    }

    const int cl = lane & 15, ch = lane >> 4;
#pragma unroll
    for (int m = 0; m < 4; ++m)
#pragma unroll
        for (int n = 0; n < 4; ++n)
#pragma unroll
            for (int r = 0; r < 4; ++r)
                C[(size_t)(m0 + wr * 64 + m * 16 + ch * 4 + r) * ldc
                  + n0 + wc * 64 + n * 16 + cl] = acc[m][n][r];
}

// ---------------- fp32 tiled GEMM (GBIAS one-off) ----------------
__global__ __launch_bounds__(256)
void gemm_tn(const float* __restrict__ A, const float* __restrict__ W,
             const float* __restrict__ b1, const float* __restrict__ b2,
             float* __restrict__ C,
             int M, int N, int K, int lda, int ldw, int ldc)
{
    __shared__ float AsT[16][68];
    __shared__ float WsT[16][68];
    const int t  = threadIdx.x;
    const int tx = t & 15, ty = t >> 4;
    const int m0 = blockIdx.y * 64, n0 = blockIdx.x * 64;
    const int lr = t >> 2;
    const int c4 = t & 3;

    float acc[4][4];
#pragma unroll
    for (int i = 0; i < 4; ++i)
#pragma unroll
        for (int j = 0; j < 4; ++j) acc[i][j] = 0.0f;

    for (int k0 = 0; k0 < K; k0 += 16) {
        float a[4], w[4];
        const int kb = k0 + c4 * 4;
        if (kb + 3 < K) {
            const float4 av = *(const float4*)(A + (size_t)(m0 + lr) * lda + kb);
            a[0] = av.x; a[1] = av.y; a[2] = av.z; a[3] = av.w;
            const float4 wv = *(const float4*)(W + (size_t)(n0 + lr) * ldw + kb);
            w[0] = wv.x; w[1] = wv.y; w[2] = wv.z; w[3] = wv.w;
        } else {
#pragma unroll
            for (int k = 0; k < 4; ++k) {
                a[k] = (kb + k < K) ? A[(size_t)(m0 + lr) * lda + kb + k] : 0.0f;
                w[k] = (kb + k < K) ? W[(size_t)(n0 + lr) * ldw + kb + k] : 0.0f;
            }
        }
        __syncthreads();
#pragma unroll
        for (int k = 0; k < 4; ++k) {
            AsT[c4 * 4 + k][lr] = a[k];
            WsT[c4 * 4 + k][lr] = w[k];
        }
        __syncthreads();
#pragma unroll
        for (int kk = 0; kk < 16; ++kk) {
            const float4 av = *(const float4*)&AsT[kk][ty * 4];
            const float4 wv = *(const float4*)&WsT[kk][tx * 4];
            acc[0][0] += av.x * wv.x; acc[0][1] += av.x * wv.y; acc[0][2] += av.x * wv.z; acc[0][3] += av.x * wv.w;
            acc[1][0] += av.y * wv.x; acc[1][1] += av.y * wv.y; acc[1][2] += av.y * wv.z; acc[1][3] += av.y * wv.w;
            acc[2][0] += av.z * wv.x; acc[2][1] += av.z * wv.y; acc[2][2] += av.z * wv.z; acc[2][3] += av.z * wv.w;
            acc[3][0] += av.w * wv.x; acc[3][1] += av.w * wv.y; acc[3][2] += av.w * wv.z; acc[3][3] += av.w * wv.w;
        }
    }

#pragma unroll
    for (int i = 0; i < 4; ++i) {
        const int m = m0 + ty * 4 + i;
#pragma unroll
        for (int j = 0; j < 4; ++j) {
            const int n = n0 + tx * 4 + j;
            float v = acc[i][j];
            if (b1) v += b1[n];
            if (b2) v += b2[n];
            C[(size_t)m * ldc + n] = v;
        }
    }
}

// ---------------- persistent encoder: se + pe chains, 16 steps ----------------
// Barrier groups: (role, b-tile) -> 16 independent groups of 16 u-blocks.
struct EncArgs {
    const ushort *WHse, *WHpe;
    const float  *xg_se;     // [512*16][1024], rows (b,t)
    const float  *enc_pos;   // [512][16][3]
    const float  *se_b1, *se_b2, *pe_b1, *pe_b2;
    const float  *pe_Wih;    // [1024][3]
    ushort       *conc;      // [16][512][512] bf16 (se cols 0:256, pe 256:512)
    float        *SE_C, *PE_C;
    unsigned int *bar;       // 16 groups x 16 steps
};

__global__ __launch_bounds__(256)
void enc_chain(EncArgs A)
{
    __shared__ ushort Hs[64 * 256], Ws[64 * 256];
    const int tid = threadIdx.x, lane = tid & 63, w = tid >> 6;
    const int role = blockIdx.x >> 7;           // 0 = se, 1 = pe
    const int b7 = blockIdx.x & 127;
    const int b0 = (b7 & 7) * 64, u0 = (b7 >> 3) * 16;
    const int grp = role * 8 + (b7 & 7);
    const int fr = lane & 15, fq = lane >> 4;
    const int u = u0 + fr;
    const int coff = role ? 256 : 0;

    stage_wtile(role ? A.WHpe : A.WHse, HID, u0, Ws, lane, w);

    const float* b1 = role ? A.pe_b1 : A.se_b1;
    const float* b2 = role ? A.pe_b2 : A.se_b2;
    float bias[4], wxs[4][3];
#pragma unroll
    for (int g = 0; g < 4; ++g) {
        bias[g] = b1[g * HID + u] + b2[g * HID + u];
        wxs[g][0] = wxs[g][1] = wxs[g][2] = 0.0f;
        if (role) {
            wxs[g][0] = A.pe_Wih[(g * HID + u) * 3 + 0];
            wxs[g][1] = A.pe_Wih[(g * HID + u) * 3 + 1];
            wxs[g][2] = A.pe_Wih[(g * HID + u) * 3 + 2];
        }
    }
    float c[4] = {0.f, 0.f, 0.f, 0.f};

    for (int t = 0; t < MENC; ++t) {
        f32x4 acc[4] = {};
        if (t > 0) {
            stage_tile(A.conc + ((size_t)(t - 1) * 512 + b0) * 512 + coff, 512, Hs, lane, w);
            __syncthreads();
            mfma_tile(Hs, Ws, acc, lane, w);
        }
#pragma unroll
        for (int r = 0; r < 4; ++r) {
            const int b = b0 + w * 16 + fq * 4 + r;
            float x0 = 0.f, x1 = 0.f, x2 = 0.f;
            if (role) {
                const float* xp = A.enc_pos + ((size_t)b * MENC + t) * 3;
                x0 = xp[0]; x1 = xp[1]; x2 = xp[2];
            }
            float gv[4];
#pragma unroll
            for (int g = 0; g < 4; ++g) {
                float v = acc[g][r] + bias[g];
                if (role) v += x0 * wxs[g][0] + x1 * wxs[g][1] + x2 * wxs[g][2];
                else      v += A.xg_se[((size_t)b * MENC + t) * 1024 + g * HID + u];
                gv[g] = v;
            }
            const float cn = sigmf(gv[1]) * c[r] + sigmf(gv[0]) * tanhf(gv[2]);
            const float hn = sigmf(gv[3]) * tanhf(cn);
            c[r] = cn;
            A.conc[((size_t)t * 512 + b) * 512 + coff + u] = f2bf(hn);
            if (t == MENC - 1) (role ? A.PE_C : A.SE_C)[(size_t)b * HID + u] = cn;
        }
        if (t != MENC - 1) gbar(A.bar + grp * MENC + t, 16);
    }
}

// ---------------- persistent mid: sd (25 steps) + fe (16 steps) ----------------
struct MidArgs {
    const ushort *WHsd, *WHfe;
    const float  *xg_sd;     // rows (b*25+t)
    const float  *xg_fe;     // rows (t*512+b)
    const float  *sd_b1, *sd_b2, *fe_b1, *fe_b2;
    const ushort *conc;
    const float  *SE_C;
    ushort       *SDB;       // [25][512][256]
    ushort       *FEB;       // [2][512][256]
    float        *FEH, *FE_C;
    unsigned int *bar;       // 16 groups x 25 steps
};

__global__ __launch_bounds__(256)
void mid_chain(MidArgs A)
{
    __shared__ ushort Hs[64 * 256], Ws[64 * 256];
    const int tid = threadIdx.x, lane = tid & 63, w = tid >> 6;
    const int role = blockIdx.x >> 7;           // 0 = sd, 1 = fe
    const int b7 = blockIdx.x & 127;
    const int b0 = (b7 & 7) * 64, u0 = (b7 >> 3) * 16;
    const int grp = role * 8 + (b7 & 7);
    const int fr = lane & 15, fq = lane >> 4;
    const int u = u0 + fr;
    const int NT = role ? MENC : HWIN;

    stage_wtile(role ? A.WHfe : A.WHsd, HID, u0, Ws, lane, w);

    const float* b1 = role ? A.fe_b1 : A.sd_b1;
    const float* b2 = role ? A.fe_b2 : A.sd_b2;
    float bias[4];
#pragma unroll
    for (int g = 0; g < 4; ++g) bias[g] = b1[g * HID + u] + b2[g * HID + u];

    float c[4];
#pragma unroll
    for (int r = 0; r < 4; ++r) {
        const int b = b0 + w * 16 + fq * 4 + r;
        c[r] = role ? 0.0f : A.SE_C[(size_t)b * HID + u];
    }

    for (int t = 0; t < NT; ++t) {
        f32x4 acc[4] = {};
        const bool doH = !(role == 1 && t == 0);
        if (doH) {
            const ushort* hsrc; int ldh;
            if (role == 0) {
                if (t == 0) { hsrc = A.conc + ((size_t)15 * 512 + b0) * 512; ldh = 512; }
                else        { hsrc = A.SDB + ((size_t)(t - 1) * 512 + b0) * HID; ldh = HID; }
            } else {
                hsrc = A.FEB + ((size_t)((t - 1) & 1) * BATCH + b0) * HID; ldh = HID;
            }
            stage_tile(hsrc, ldh, Hs, lane, w);
            __syncthreads();
            mfma_tile(Hs, Ws, acc, lane, w);
        }
#pragma unroll
        for (int r = 0; r < 4; ++r) {
            const int b = b0 + w * 16 + fq * 4 + r;
            float gv[4];
#pragma unroll
            for (int g = 0; g < 4; ++g) {
                float v = acc[g][r] + bias[g];
                if (role) v += A.xg_fe[((size_t)t * 512 + b) * 1024 + g * HID + u];
                else      v += A.xg_sd[((size_t)b * HWIN + t) * 1024 + g * HID + u];
                gv[g] = v;
            }
            const float cn = sigmf(gv[1]) * c[r] + sigmf(gv[0]) * tanhf(gv[2]);
            const float hn = sigmf(gv[3]) * tanhf(cn);
            c[r] = cn;
            if (role == 0) {
                A.SDB[((size_t)t * 512 + b) * HID + u] = f2bf(hn);
            } else {
                A.FEB[((size_t)(t & 1) * BATCH + b) * HID + u] = f2bf(hn);
                if (t == MENC - 1) {
                    A.FEH[(size_t)b * HID + u] = hn;
                    A.FE_C[(size_t)b * HID + u] = cn;
                }
            }
        }
        if (t != NT - 1) gbar(A.bar + grp * HWIN + t, 16);
    }
}

// ---------------- persistent decoder: pd + fd + tail, 25 steps ----------------
// Barrier groups: b-tile -> 8 independent groups of 16 u-blocks, 2 bars/step.
struct DecArgs {
    const ushort *WHpd;
    const ushort *WFDh;      // fd_Wih cols 256:512 view (ld 512)
    const ushort *peF;       // conc[15] + 256, ld 512
    const float  *PE_C, *FE_C, *GBIAS;
    const float  *xh2;       // [25*512][1024], rows (t,b)
    const float  *pd_b1, *pd_b2, *pd_Wih;
    const float  *G, *c3, *dec_pos;
    ushort       *H1;        // [2][512][256]
    float        *DELTA;     // [25][512][3], pre-zeroed
    float        *out;       // [512][25][3]
    unsigned int *bar;       // 8 groups x 50
};

__global__ __launch_bounds__(256)
void dec_chain(DecArgs A)
{
    __shared__ ushort Wpd[64 * 256], Wfd[64 * 256], Hs[64 * 256];
    __shared__ float pred_lds[192];
    const int tid = threadIdx.x, lane = tid & 63, w = tid >> 6;
    const int grp = blockIdx.x & 7;
    const int b0 = grp * 64, u0 = (blockIdx.x >> 3) * 16;
    const int fr = lane & 15, fq = lane >> 4;
    const int u = u0 + fr;

    stage_wtile(A.WHpd, HID, u0, Wpd, lane, w);
    stage_wtile(A.WFDh, 512, u0, Wfd, lane, w);

    float pdb[4], wxs[4][3], gb[4][4], cf[4], c1[4], Gu[3];
#pragma unroll
    for (int g = 0; g < 4; ++g) {
        pdb[g] = A.pd_b1[g * HID + u] + A.pd_b2[g * HID + u];
        wxs[g][0] = A.pd_Wih[(g * HID + u) * 3 + 0];
        wxs[g][1] = A.pd_Wih[(g * HID + u) * 3 + 1];
        wxs[g][2] = A.pd_Wih[(g * HID + u) * 3 + 2];
    }
#pragma unroll
    for (int r = 0; r < 4; ++r) {
        const int b = b0 + w * 16 + fq * 4 + r;
        c1[r] = A.PE_C[(size_t)b * HID + u];
        cf[r] = A.FE_C[(size_t)b * HID + u];
#pragma unroll
        for (int g = 0; g < 4; ++g) gb[r][g] = A.GBIAS[(size_t)b * 1024 + g * HID + u];
    }
    Gu[0] = A.G[0 * HID + u]; Gu[1] = A.G[1 * HID + u]; Gu[2] = A.G[2 * HID + u];
    const float c3r = (tid < 192) ? A.c3[tid % 3] : 0.0f;
    if (tid < 192) pred_lds[tid] = A.dec_pos[(size_t)(b0 + tid / 3) * 3 + tid % 3];
    __syncthreads();

    for (int t = 0; t < HWIN; ++t) {
        // ---- phase A: pd cell ----
        {
            f32x4 acc[4] = {};
            const ushort* hsrc; int ldh;
            if (t == 0) { hsrc = A.peF + (size_t)b0 * 512; ldh = 512; }
            else        { hsrc = A.H1 + ((size_t)((t - 1) & 1) * BATCH + b0) * HID; ldh = HID; }
            stage_tile(hsrc, ldh, Hs, lane, w);
            __syncthreads();
            mfma_tile(Hs, Wpd, acc, lane, w);
#pragma unroll
            for (int r = 0; r < 4; ++r) {
                const int bl = w * 16 + fq * 4 + r, b = b0 + bl;
                const float x0 = pred_lds[bl * 3 + 0];
                const float x1 = pred_lds[bl * 3 + 1];
                const float x2 = pred_lds[bl * 3 + 2];
                float gv[4];
#pragma unroll
                for (int g = 0; g < 4; ++g)
                    gv[g] = acc[g][r] + pdb[g] + x0 * wxs[g][0] + x1 * wxs[g][1] + x2 * wxs[g][2];
                const float cn = sigmf(gv[1]) * c1[r] + sigmf(gv[0]) * tanhf(gv[2]);
                const float hn = sigmf(gv[3]) * tanhf(cn);
                c1[r] = cn;
                A.H1[((size_t)(t & 1) * BATCH + b) * HID + u] = f2bf(hn);
            }
        }
        gbar(A.bar + grp * 2 * HWIN + 2 * t, 16);
        // ---- phase B: fd cell + tail partials ----
        {
            f32x4 acc[4] = {};
            stage_tile(A.H1 + ((size_t)(t & 1) * BATCH + b0) * HID, HID, Hs, lane, w);
            __syncthreads();
            mfma_tile(Hs, Wfd, acc, lane, w);
#pragma unroll
            for (int r = 0; r < 4; ++r) {
                const int b = b0 + w * 16 + fq * 4 + r;
                float gv[4];
#pragma unroll
                for (int g = 0; g < 4; ++g)
                    gv[g] = acc[g][r] + A.xh2[((size_t)t * 512 + b) * 1024 + g * HID + u] + gb[r][g];
                const float cn = sigmf(gv[1]) * cf[r] + sigmf(gv[0]) * tanhf(gv[2]);
                const float hn = sigmf(gv[3]) * tanhf(cn);
                float p0 = hn * Gu[0], p1 = hn * Gu[1], p2 = hn * Gu[2];
#pragma unroll
                for (int s = 1; s < 16; s <<= 1) {
                    p0 += __shfl_xor(p0, s);
                    p1 += __shfl_xor(p1, s);
                    p2 += __shfl_xor(p2, s);
                }
                if (fr == 0) {
                    float* d = A.DELTA + ((size_t)t * 512 + b) * 3;
                    atomicAdd(d + 0, p0); atomicAdd(d + 1, p1); atomicAdd(d + 2, p2);
                }
            }
        }
        gbar(A.bar + grp * 2 * HWIN + 2 * t + 1, 16);
        // ---- pred update + out ----
        if (tid < 192) {
            pred_lds[tid] += A.DELTA[((size_t)t * 512 + b0 + tid / 3) * 3 + tid % 3] + c3r;
            if (u0 == 0)
                A.out[((size_t)(b0 + tid / 3) * HWIN + t) * 3 + tid % 3] = pred_lds[tid];
        }
        __syncthreads();
    }
}

// ---------------- G = out_W @ f2_W, c3 = out_b + out_W @ f2_b ----------------
__global__ __launch_bounds__(256)
void precompute_G(const float* __restrict__ f2W, const float* __restrict__ f2b,
                  const float* __restrict__ outW, const float* __restrict__ outb,
                  float* __restrict__ G, float* __restrict__ c3)
{
    const int k = threadIdx.x;
    float g0 = 0.f, g1 = 0.f, g2 = 0.f;
    for (int n = 0; n < HID; ++n) {
        const float w = f2W[n * HID + k];
        g0 += outW[n] * w;
        g1 += outW[HID + n] * w;
        g2 += outW[2 * HID + n] * w;
    }
    G[k] = g0; G[HID + k] = g1; G[2 * HID + k] = g2;
    if (k < 3) {
        float s = outb[k];
        for (int n = 0; n < HID; ++n) s += outW[k * HID + n] * f2b[n];
        c3[k] = s;
    }
}

extern "C" void kernel_launch(void* const* d_in, const int* in_sizes, int n_in,
                              void* d_out, int out_size, void* d_ws, size_t ws_size,
                              hipStream_t stream)
{
    (void)in_sizes; (void)n_in; (void)out_size; (void)ws_size;
    const float* enc_pos = (const float*)d_in[0];
    const float* enc_sal = (const float*)d_in[1];
    const float* dec_pos = (const float*)d_in[2];
    const float* dec_sal = (const float*)d_in[3];
    const float *pe_Wih = (const float*)d_in[4],  *pe_Whh = (const float*)d_in[5],
                *pe_bih = (const float*)d_in[6],  *pe_bhh = (const float*)d_in[7];
    const float *se_Wih = (const float*)d_in[8],  *se_Whh = (const float*)d_in[9],
                *se_bih = (const float*)d_in[10], *se_bhh = (const float*)d_in[11];
    const float *fe_Wih = (const float*)d_in[12], *fe_Whh = (const float*)d_in[13],
                *fe_bih = (const float*)d_in[14], *fe_bhh = (const float*)d_in[15];
    const float *pd_Wih = (const float*)d_in[16], *pd_Whh = (const float*)d_in[17],
                *pd_bih = (const float*)d_in[18], *pd_bhh = (const float*)d_in[19];
    const float *sd_Wih = (const float*)d_in[20], *sd_Whh = (const float*)d_in[21],
                *sd_bih = (const float*)d_in[22], *sd_bhh = (const float*)d_in[23];
    const float *fd_Wih = (const float*)d_in[24], *fd_Whh = (const float*)d_in[25],
                *fd_bih = (const float*)d_in[26], *fd_bhh = (const float*)d_in[27];
    const float *f2_W = (const float*)d_in[28], *f2_b = (const float*)d_in[29];
    const float *out_W = (const float*)d_in[30], *out_b = (const float*)d_in[31];
    float* out = (float*)d_out;
    float* ws  = (float*)d_ws;

    // ---- workspace (float units) ----
    size_t off = 0;
    float* XG_SE = ws + off; off += (size_t)8192 * 1024;    // se x-proj, rows (b,t)
    float* XG_FE = ws + off; off += (size_t)8192 * 1024;    // fe x-proj, rows (t,b)
    float* BIG   = ws + off; off += (size_t)12800 * 1024;   // sd x-proj, rows (b,t)
    float* BIG2  = ws + off; off += (size_t)12800 * 1024;   // fd Xh2, rows (t,b)
    float* GBIAS = ws + off; off += (size_t)BATCH * 1024;
    float* PE_C  = ws + off; off += BH;
    float* SE_C  = ws + off; off += BH;
    float* FE_C  = ws + off; off += BH;
    float* FEH   = ws + off; off += BH;
    float* Gm    = ws + off; off += 1024;
    float* C3    = ws + off; off += 8;
    float* DELTA = ws + off; off += (size_t)HWIN * BATCH * 3 + 64;
    unsigned int* BAR = (unsigned int*)(ws + off); off += 1280;
    ushort* ABUF = (ushort*)(ws + off); off += ((size_t)12800 * 4096) / 2;
    ushort* WSE  = (ushort*)(ws + off); off += ((size_t)1024 * 4096) / 2;
    ushort* WSD  = (ushort*)(ws + off); off += ((size_t)1024 * 4096) / 2;
    ushort* WFE  = (ushort*)(ws + off); off += ((size_t)1024 * 512) / 2;
    ushort* WFD  = (ushort*)(ws + off); off += ((size_t)1024 * 512) / 2;
    ushort* WHpe = (ushort*)(ws + off); off += ((size_t)1024 * 256) / 2;
    ushort* WHse = (ushort*)(ws + off); off += ((size_t)1024 * 256) / 2;
    ushort* WHfe = (ushort*)(ws + off); off += ((size_t)1024 * 256) / 2;
    ushort* WHsd = (ushort*)(ws + off); off += ((size_t)1024 * 256) / 2;
    ushort* WHpd = (ushort*)(ws + off); off += ((size_t)1024 * 256) / 2;
    ushort* CONC = (ushort*)(ws + off); off += ((size_t)MENC * 512 * 512) / 2;  // [t][b][512]
    ushort* SDB  = (ushort*)(ws + off); off += ((size_t)HWIN * BH) / 2;         // [t][b][256]
    ushort* FEB  = (ushort*)(ws + off); off += (size_t)BH;                      // [2][512][256]
    ushort* H1   = (ushort*)(ws + off); off += (size_t)BH;                      // [2][512][256]

    hipMemsetAsync(DELTA, 0, (size_t)HWIN * BATCH * 3 * 4, stream);
    hipMemsetAsync(BAR, 0, 1280 * 4, stream);

    auto cvt = [&](const float* in, ushort* outp, size_t n) {
        const int n4 = (int)(n / 4);
        cvt_f32_bf16<<<(n4 + 255) / 256, 256, 0, stream>>>(in, outp, n4);
    };
    auto mgemm = [&](const ushort* A, const ushort* W, float* C,
                     int M, int N, int K, int lda, int ldw, int ldc) {
        gemm_mfma_bt<<<dim3(N / 128, M / 128), 256, 0, stream>>>(A, W, C, M, N, K, lda, ldw, ldc);
    };

    // ---- one-time conversions / precomputes ----
    cvt(se_Wih, WSE, (size_t)1024 * SALSZ);
    cvt(sd_Wih, WSD, (size_t)1024 * SALSZ);
    cvt(fe_Wih, WFE, (size_t)1024 * 512);
    cvt(fd_Wih, WFD, (size_t)1024 * 512);
    cvt(pe_Whh, WHpe, (size_t)1024 * 256);
    cvt(se_Whh, WHse, (size_t)1024 * 256);
    cvt(fe_Whh, WHfe, (size_t)1024 * 256);
    cvt(sd_Whh, WHsd, (size_t)1024 * 256);
    cvt(pd_Whh, WHpd, (size_t)1024 * 256);
    cvt(enc_sal, ABUF, (size_t)8192 * SALSZ);
    precompute_G<<<1, 256, 0, stream>>>(f2_W, f2_b, out_W, out_b, Gm, C3);

    // ---- se x-projection ----
    mgemm(ABUF, WSE, XG_SE, 8192, 1024, SALSZ, SALSZ, SALSZ, 1024);

    // ---- persistent encoder (se + pe) ----
    {
        EncArgs a;
        a.WHse = WHse; a.WHpe = WHpe; a.xg_se = XG_SE; a.enc_pos = enc_pos;
        a.se_b1 = se_bih; a.se_b2 = se_bhh; a.pe_b1 = pe_bih; a.pe_b2 = pe_bhh;
        a.pe_Wih = pe_Wih; a.conc = CONC; a.SE_C = SE_C; a.PE_C = PE_C;
        a.bar = BAR;
        enc_chain<<<256, 256, 0, stream>>>(a);
    }

    // ---- fe x-proj (rows t,b) + sd x-proj ----
    mgemm(CONC, WFE, XG_FE, 8192, 1024, 512, 512, 512, 1024);
    cvt(dec_sal, ABUF, (size_t)12800 * SALSZ);
    mgemm(ABUF, WSD, BIG, 12800, 1024, SALSZ, SALSZ, SALSZ, 1024);

    // ---- persistent mid (sd + fe) ----
    {
        MidArgs a;
        a.WHsd = WHsd; a.WHfe = WHfe; a.xg_sd = BIG; a.xg_fe = XG_FE;
        a.sd_b1 = sd_bih; a.sd_b2 = sd_bhh; a.fe_b1 = fe_bih; a.fe_b2 = fe_bhh;
        a.conc = CONC; a.SE_C = SE_C; a.SDB = SDB; a.FEB = FEB;
        a.FEH = FEH; a.FE_C = FE_C; a.bar = BAR + 256;
        mid_chain<<<256, 256, 0, stream>>>(a);
    }

    // ---- fd precomputations ----
    mgemm(SDB, WFD, BIG2, 12800, 1024, HID, HID, 512, 1024);   // Xh2, rows (t,b)
    gemm_tn<<<dim3(16, 8), 256, 0, stream>>>(FEH, fd_Whh, fd_bih, fd_bhh, GBIAS,
                                             BATCH, 1024, HID, HID, HID, 1024);

    // ---- persistent decoder (pd + fd + tail) ----
    {
        DecArgs a;
        a.WHpd = WHpd; a.WFDh = WFD + 256;
        a.peF = CONC + ((size_t)15 * 512) * 512 + 256;
        a.PE_C = PE_C; a.FE_C = FE_C; a.GBIAS = GBIAS; a.xh2 = BIG2;
        a.pd_b1 = pd_bih; a.pd_b2 = pd_bhh; a.pd_Wih = pd_Wih;
        a.G = Gm; a.c3 = C3; a.dec_pos = dec_pos;
        a.H1 = H1; a.DELTA = DELTA; a.out = out; a.bar = BAR + 656;
        dec_chain<<<128, 256, 0, stream>>>(a);
    }
}

// Round 6
// 1440.790 us; speedup vs baseline: 1.4362x; 1.0650x over previous
//
#include <hip/hip_runtime.h>

#define HID 256
#define BATCH 512
#define MENC 16
#define HWIN 25
#define SALSZ 4096
#define BH (BATCH * HID)   // 131072

typedef __attribute__((ext_vector_type(8))) short bf16x8;
typedef __attribute__((ext_vector_type(4))) float f32x4;

__device__ __forceinline__ float sigmf(float x) { return 1.0f / (1.0f + __expf(-x)); }
__device__ __forceinline__ ushort f2bf(float f) {
    uint32_t u = __float_as_uint(f);
    return (ushort)((u + 0x7fffu + ((u >> 16) & 1u)) >> 16);   // RNE
}

#define GLOAD_LDS(gp, lp) \
    __builtin_amdgcn_global_load_lds((const __attribute__((address_space(1))) void*)(gp), \
                                     (__attribute__((address_space(3))) void*)(lp), 16, 0, 0)

// ---- group-local device barrier: relaxed spin, one acquire fence at the end ----
__device__ __forceinline__ void gbar(unsigned int* slot, unsigned int nblk)
{
    __syncthreads();
    if (threadIdx.x == 0) {
        __threadfence();                          // release prior writes (agent)
        atomicAdd(slot, 1u);
        while (__hip_atomic_load(slot, __ATOMIC_RELAXED, __HIP_MEMORY_SCOPE_AGENT) < nblk)
            __builtin_amdgcn_s_sleep(1);
        __builtin_amdgcn_fence(__ATOMIC_ACQUIRE, "agent");   // one invalidate
    }
    __syncthreads();
}

// ---- W tile staging: [64][256] bf16, XOR-swizzled 16B units, via global_load_lds ----
// Called by 4 cooperating waves (wq = 0..3). LDS row vn = g*16+ul <- global row g*256+u0+ul.
__device__ __forceinline__ void stage_wtile(const ushort* Wsrc, int ldw, int u0,
                                            ushort* lds, int lane, int wq)
{
    const int sub = lane >> 5, uu = lane & 31;
#pragma unroll
    for (int i = 0; i < 8; ++i) {
        const int row = i * 8 + wq * 2 + sub;
        const int su  = uu ^ (row & 7);
        const int gr  = (row >> 4) * HID + u0 + (row & 15);
        GLOAD_LDS(Wsrc + (size_t)gr * ldw + su * 8, lds + i * 2048 + wq * 512);
    }
}

// ---- LSTM cell quarter: H (16 b-rows) straight from GLOBAL into A-fragments,
// ---- W (16u x 4 gates) from swizzled LDS tile. 32 MFMA per wave.
__device__ __forceinline__ void cell_g(const ushort* hrow0, int ldh,
                                       const ushort* WsL, f32x4 acc[4], int lane)
{
    const int fr = lane & 15, fq = lane >> 4;
    const ushort* hrow = hrow0 + (size_t)fr * ldh;
#pragma unroll
    for (int ks = 0; ks < 8; ++ks) {
        const int ku = ks * 4 + fq;
        const bf16x8 af = *(const bf16x8*)(hrow + ku * 8);
#pragma unroll
        for (int g = 0; g < 4; ++g) {
            const int vr = g * 16 + fr;
            const bf16x8 bf = *(const bf16x8*)(WsL + vr * 256 + (ku ^ (vr & 7)) * 8);
            acc[g] = __builtin_amdgcn_mfma_f32_16x16x32_bf16(af, bf, acc[g], 0, 0, 0);
        }
    }
}

// ---------------- fp32 -> bf16 ----------------
__global__ __launch_bounds__(256)
void cvt_f32_bf16(const float* __restrict__ in, ushort* __restrict__ out, int n4)
{
    const int i = blockIdx.x * 256 + threadIdx.x;
    if (i >= n4) return;
    const float4 v = *(const float4*)(in + (size_t)i * 4);
    *(ushort4*)(out + (size_t)i * 4) = make_ushort4(f2bf(v.x), f2bf(v.y), f2bf(v.z), f2bf(v.w));
}

// ---------------- big bf16 MFMA GEMM: C[M,N] = A[M,K] @ W[N,K]^T (m97) ----------------
__global__ __launch_bounds__(256)
void gemm_mfma_bt(const ushort* __restrict__ A, const ushort* __restrict__ W,
                  float* __restrict__ C, int M, int N, int K,
                  int lda, int ldw, int ldc)
{
    __shared__ ushort As[128 * 32];
    __shared__ ushort Bs[128 * 32];
    const int t    = threadIdx.x;
    const int lane = t & 63, wid = t >> 6;
    const int m0 = blockIdx.y * 128, n0 = blockIdx.x * 128;
    const int wr = wid >> 1, wc = wid & 1;

    f32x4 acc[4][4] = {};

    const int sr = wid * 16 + (lane >> 2);
    const int sk = (lane & 3) * 8;
    const ushort* Ag = A + (size_t)(m0 + sr) * lda + sk;
    const ushort* Wg = W + (size_t)(n0 + sr) * ldw + sk;
    ushort* Al = As + wid * 512;
    ushort* Bl = Bs + wid * 512;

    const int fr = lane & 15;
    const int fk = (lane >> 4) * 8;

    for (int k0 = 0; k0 < K; k0 += 32) {
        GLOAD_LDS(Ag,                    Al);
        GLOAD_LDS(Ag + (size_t)64 * lda, Al + 2048);
        GLOAD_LDS(Wg,                    Bl);
        GLOAD_LDS(Wg + (size_t)64 * ldw, Bl + 2048);
        Ag += 32; Wg += 32;
        __syncthreads();

        bf16x8 af[4], bfr[4];
#pragma unroll
        for (int m = 0; m < 4; ++m)
            af[m] = *(const bf16x8*)(As + (wr * 64 + m * 16 + fr) * 32 + fk);
#pragma unroll
        for (int n = 0; n < 4; ++n)
            bfr[n] = *(const bf16x8*)(Bs + (wc * 64 + n * 16 + fr) * 32 + fk);
#pragma unroll
        for (int m = 0; m < 4; ++m)
#pragma unroll
            for (int n = 0; n < 4; ++n)
                acc[m][n] = __builtin_amdgcn_mfma_f32_16x16x32_bf16(af[m], bfr[n], acc[m][n], 0, 0, 0);
        __syncthreads();
    }

    const int cl = lane & 15, ch = lane >> 4;
#pragma unroll
    for (int m = 0; m < 4; ++m)
#pragma unroll
        for (int n = 0; n < 4; ++n)
#pragma unroll
            for (int r = 0; r < 4; ++r)
                C[(size_t)(m0 + wr * 64 + m * 16 + ch * 4 + r) * ldc
                  + n0 + wc * 64 + n * 16 + cl] = acc[m][n][r];
}

// ---------------- fp32 tiled GEMM (GBIAS one-off) ----------------
__global__ __launch_bounds__(256)
void gemm_tn(const float* __restrict__ A, const float* __restrict__ W,
             const float* __restrict__ b1, const float* __restrict__ b2,
             float* __restrict__ C,
             int M, int N, int K, int lda, int ldw, int ldc)
{
    __shared__ float AsT[16][68];
    __shared__ float WsT[16][68];
    const int t  = threadIdx.x;
    const int tx = t & 15, ty = t >> 4;
    const int m0 = blockIdx.y * 64, n0 = blockIdx.x * 64;
    const int lr = t >> 2;
    const int c4 = t & 3;

    float acc[4][4];
#pragma unroll
    for (int i = 0; i < 4; ++i)
#pragma unroll
        for (int j = 0; j < 4; ++j) acc[i][j] = 0.0f;

    for (int k0 = 0; k0 < K; k0 += 16) {
        float a[4], w[4];
        const int kb = k0 + c4 * 4;
        if (kb + 3 < K) {
            const float4 av = *(const float4*)(A + (size_t)(m0 + lr) * lda + kb);
            a[0] = av.x; a[1] = av.y; a[2] = av.z; a[3] = av.w;
            const float4 wv = *(const float4*)(W + (size_t)(n0 + lr) * ldw + kb);
            w[0] = wv.x; w[1] = wv.y; w[2] = wv.z; w[3] = wv.w;
        } else {
#pragma unroll
            for (int k = 0; k < 4; ++k) {
                a[k] = (kb + k < K) ? A[(size_t)(m0 + lr) * lda + kb + k] : 0.0f;
                w[k] = (kb + k < K) ? W[(size_t)(n0 + lr) * ldw + kb + k] : 0.0f;
            }
        }
        __syncthreads();
#pragma unroll
        for (int k = 0; k < 4; ++k) {
            AsT[c4 * 4 + k][lr] = a[k];
            WsT[c4 * 4 + k][lr] = w[k];
        }
        __syncthreads();
#pragma unroll
        for (int kk = 0; kk < 16; ++kk) {
            const float4 av = *(const float4*)&AsT[kk][ty * 4];
            const float4 wv = *(const float4*)&WsT[kk][tx * 4];
            acc[0][0] += av.x * wv.x; acc[0][1] += av.x * wv.y; acc[0][2] += av.x * wv.z; acc[0][3] += av.x * wv.w;
            acc[1][0] += av.y * wv.x; acc[1][1] += av.y * wv.y; acc[1][2] += av.y * wv.z; acc[1][3] += av.y * wv.w;
            acc[2][0] += av.z * wv.x; acc[2][1] += av.z * wv.y; acc[2][2] += av.z * wv.z; acc[2][3] += av.z * wv.w;
            acc[3][0] += av.w * wv.x; acc[3][1] += av.w * wv.y; acc[3][2] += av.w * wv.z; acc[3][3] += av.w * wv.w;
        }
    }

#pragma unroll
    for (int i = 0; i < 4; ++i) {
        const int m = m0 + ty * 4 + i;
#pragma unroll
        for (int j = 0; j < 4; ++j) {
            const int n = n0 + tx * 4 + j;
            float v = acc[i][j];
            if (b1) v += b1[n];
            if (b2) v += b2[n];
            C[(size_t)m * ldc + n] = v;
        }
    }
}

// ---------------- persistent encoder: se + pe chains, 16 steps ----------------
// 1024-thread blocks: 64 b x 64 u (4 W-tiles in LDS). Barrier degree 4.
struct EncArgs {
    const ushort *WHse, *WHpe;
    const float  *xg_se;     // [512*16][1024], rows (b,t)
    const float  *enc_pos;   // [512][16][3]
    const float  *se_b1, *se_b2, *pe_b1, *pe_b2;
    const float  *pe_Wih;    // [1024][3]
    ushort       *conc;      // [16][512][512] (se cols 0:256, pe 256:512)
    float        *SE_C, *PE_C;
    unsigned int *bar;       // 16 groups x 16
};

__global__ __launch_bounds__(1024)
void enc_chain(EncArgs A)
{
    __shared__ ushort Ws[4][64 * 256];   // 128 KB
    const int tid = threadIdx.x, lane = tid & 63, w = tid >> 6;
    const int role  = blockIdx.x >> 5;         // 0 = se, 1 = pe
    const int rem   = blockIdx.x & 31;
    const int btile = rem & 7, usup = rem >> 3;
    const int b0 = btile * 64, ub = usup * 64;
    const int usub = w & 3, bsub = w >> 2;
    const int u0t = ub + usub * 16;
    const int grp = role * 8 + btile;
    const int fr = lane & 15, fq = lane >> 4;
    const int u = u0t + fr;
    const int coff = role ? 256 : 0;

    stage_wtile(role ? A.WHpe : A.WHse, HID, u0t, Ws[usub], lane, bsub);

    const float* b1 = role ? A.pe_b1 : A.se_b1;
    const float* b2 = role ? A.pe_b2 : A.se_b2;
    float bias[4], wxs[4][3];
#pragma unroll
    for (int g = 0; g < 4; ++g) {
        bias[g] = b1[g * HID + u] + b2[g * HID + u];
        wxs[g][0] = wxs[g][1] = wxs[g][2] = 0.0f;
        if (role) {
            wxs[g][0] = A.pe_Wih[(g * HID + u) * 3 + 0];
            wxs[g][1] = A.pe_Wih[(g * HID + u) * 3 + 1];
            wxs[g][2] = A.pe_Wih[(g * HID + u) * 3 + 2];
        }
    }
    float c[4] = {0.f, 0.f, 0.f, 0.f};
    __syncthreads();   // W tiles staged

    for (int t = 0; t < MENC; ++t) {
        f32x4 acc[4] = {};
        if (t > 0)
            cell_g(A.conc + ((size_t)(t - 1) * 512 + b0 + bsub * 16) * 512 + coff, 512,
                   Ws[usub], acc, lane);
#pragma unroll
        for (int r = 0; r < 4; ++r) {
            const int b = b0 + bsub * 16 + fq * 4 + r;
            float x0 = 0.f, x1 = 0.f, x2 = 0.f;
            if (role) {
                const float* xp = A.enc_pos + ((size_t)b * MENC + t) * 3;
                x0 = xp[0]; x1 = xp[1]; x2 = xp[2];
            }
            float gv[4];
#pragma unroll
            for (int g = 0; g < 4; ++g) {
                float v = acc[g][r] + bias[g];
                if (role) v += x0 * wxs[g][0] + x1 * wxs[g][1] + x2 * wxs[g][2];
                else      v += A.xg_se[((size_t)b * MENC + t) * 1024 + g * HID + u];
                gv[g] = v;
            }
            const float cn = sigmf(gv[1]) * c[r] + sigmf(gv[0]) * tanhf(gv[2]);
            const float hn = sigmf(gv[3]) * tanhf(cn);
            c[r] = cn;
            A.conc[((size_t)t * 512 + b) * 512 + coff + u] = f2bf(hn);
            if (t == MENC - 1) (role ? A.PE_C : A.SE_C)[(size_t)b * HID + u] = cn;
        }
        if (t != MENC - 1) gbar(A.bar + grp * MENC + t, 4);
    }
}

// ---------------- persistent mid: sd (25) + fe (16) ----------------
struct MidArgs {
    const ushort *WHsd, *WHfe;
    const float  *xg_sd;     // rows (b*25+t)
    const float  *xg_fe;     // rows (t*512+b)
    const float  *sd_b1, *sd_b2, *fe_b1, *fe_b2;
    const ushort *conc;
    const float  *SE_C;
    ushort       *SDB;       // [25][512][256]
    ushort       *FEB;       // [2][512][256]
    float        *FEH, *FE_C;
    unsigned int *bar;       // 16 groups x 25
};

__global__ __launch_bounds__(1024)
void mid_chain(MidArgs A)
{
    __shared__ ushort Ws[4][64 * 256];   // 128 KB
    const int tid = threadIdx.x, lane = tid & 63, w = tid >> 6;
    const int role  = blockIdx.x >> 5;         // 0 = sd, 1 = fe
    const int rem   = blockIdx.x & 31;
    const int btile = rem & 7, usup = rem >> 3;
    const int b0 = btile * 64, ub = usup * 64;
    const int usub = w & 3, bsub = w >> 2;
    const int u0t = ub + usub * 16;
    const int grp = role * 8 + btile;
    const int fr = lane & 15, fq = lane >> 4;
    const int u = u0t + fr;
    const int NT = role ? MENC : HWIN;

    stage_wtile(role ? A.WHfe : A.WHsd, HID, u0t, Ws[usub], lane, bsub);

    const float* b1 = role ? A.fe_b1 : A.sd_b1;
    const float* b2 = role ? A.fe_b2 : A.sd_b2;
    float bias[4];
#pragma unroll
    for (int g = 0; g < 4; ++g) bias[g] = b1[g * HID + u] + b2[g * HID + u];

    float c[4];
#pragma unroll
    for (int r = 0; r < 4; ++r) {
        const int b = b0 + bsub * 16 + fq * 4 + r;
        c[r] = role ? 0.0f : A.SE_C[(size_t)b * HID + u];
    }
    __syncthreads();

    for (int t = 0; t < NT; ++t) {
        f32x4 acc[4] = {};
        if (role == 0) {
            if (t == 0) cell_g(A.conc + ((size_t)15 * 512 + b0 + bsub * 16) * 512, 512,
                               Ws[usub], acc, lane);
            else        cell_g(A.SDB + ((size_t)(t - 1) * 512 + b0 + bsub * 16) * HID, HID,
                               Ws[usub], acc, lane);
        } else if (t > 0) {
            cell_g(A.FEB + ((size_t)((t - 1) & 1) * BATCH + b0 + bsub * 16) * HID, HID,
                   Ws[usub], acc, lane);
        }
#pragma unroll
        for (int r = 0; r < 4; ++r) {
            const int b = b0 + bsub * 16 + fq * 4 + r;
            float gv[4];
#pragma unroll
            for (int g = 0; g < 4; ++g) {
                float v = acc[g][r] + bias[g];
                if (role) v += A.xg_fe[((size_t)t * 512 + b) * 1024 + g * HID + u];
                else      v += A.xg_sd[((size_t)b * HWIN + t) * 1024 + g * HID + u];
                gv[g] = v;
            }
            const float cn = sigmf(gv[1]) * c[r] + sigmf(gv[0]) * tanhf(gv[2]);
            const float hn = sigmf(gv[3]) * tanhf(cn);
            c[r] = cn;
            if (role == 0) {
                A.SDB[((size_t)t * 512 + b) * HID + u] = f2bf(hn);
            } else {
                A.FEB[((size_t)(t & 1) * BATCH + b) * HID + u] = f2bf(hn);
                if (t == MENC - 1) {
                    A.FEH[(size_t)b * HID + u] = hn;
                    A.FE_C[(size_t)b * HID + u] = cn;
                }
            }
        }
        if (t != NT - 1) gbar(A.bar + grp * HWIN + t, 16 / 4);
    }
}

// ---------------- persistent decoder: pd + fd + tail, 25 steps ----------------
// 512-thread blocks: 64 b x 32 u, Wpd+Wfd resident (128 KB). Degree 8, 2 bars/step.
struct DecArgs {
    const ushort *WHpd;
    const ushort *WFDh;      // fd_Wih cols 256:512 view (ld 512)
    const ushort *peF;       // conc[15] + 256, ld 512
    const float  *PE_C, *FE_C, *GBIAS;
    const float  *xh2;       // [25*512][1024], rows (t,b)
    const float  *pd_b1, *pd_b2, *pd_Wih;
    const float  *G, *c3, *dec_pos;
    ushort       *H1;        // [2][512][256]
    float        *DELTA;     // [25][512][3], pre-zeroed
    float        *out;       // [512][25][3]
    unsigned int *bar;       // 8 groups x 50
};

__global__ __launch_bounds__(512)
void dec_chain(DecArgs A)
{
    __shared__ ushort Wpd[2][64 * 256], Wfd[2][64 * 256];   // 128 KB
    __shared__ float pred_lds[192];
    const int tid = threadIdx.x, lane = tid & 63, w = tid >> 6;
    const int btile = blockIdx.x & 7, usup = blockIdx.x >> 3;
    const int b0 = btile * 64, ub = usup * 32;
    const int usub = w & 1, bsub = w >> 1;
    const int u0t = ub + usub * 16;
    const int fr = lane & 15, fq = lane >> 4;
    const int u = u0t + fr;

    stage_wtile(A.WHpd, HID, u0t, Wpd[usub], lane, bsub);
    stage_wtile(A.WFDh, 512, u0t, Wfd[usub], lane, bsub);

    float pdb[4], wxs[4][3], gb[4][4], cf[4], c1[4], Gu[3];
#pragma unroll
    for (int g = 0; g < 4; ++g) {
        pdb[g] = A.pd_b1[g * HID + u] + A.pd_b2[g * HID + u];
        wxs[g][0] = A.pd_Wih[(g * HID + u) * 3 + 0];
        wxs[g][1] = A.pd_Wih[(g * HID + u) * 3 + 1];
        wxs[g][2] = A.pd_Wih[(g * HID + u) * 3 + 2];
    }
#pragma unroll
    for (int r = 0; r < 4; ++r) {
        const int b = b0 + bsub * 16 + fq * 4 + r;
        c1[r] = A.PE_C[(size_t)b * HID + u];
        cf[r] = A.FE_C[(size_t)b * HID + u];
#pragma unroll
        for (int g = 0; g < 4; ++g) gb[r][g] = A.GBIAS[(size_t)b * 1024 + g * HID + u];
    }
    Gu[0] = A.G[0 * HID + u]; Gu[1] = A.G[1 * HID + u]; Gu[2] = A.G[2 * HID + u];
    const float c3r = (tid < 192) ? A.c3[tid % 3] : 0.0f;
    if (tid < 192) pred_lds[tid] = A.dec_pos[(size_t)(b0 + tid / 3) * 3 + tid % 3];
    __syncthreads();

    for (int t = 0; t < HWIN; ++t) {
        // prefetch this step's xh2 slice (used in phase B; hides under phase A+bar)
        float xh[4][4];
#pragma unroll
        for (int r = 0; r < 4; ++r) {
            const int b = b0 + bsub * 16 + fq * 4 + r;
#pragma unroll
            for (int g = 0; g < 4; ++g)
                xh[r][g] = A.xh2[((size_t)t * 512 + b) * 1024 + g * HID + u];
        }
        // ---- phase A: pd cell ----
        {
            f32x4 acc[4] = {};
            if (t == 0) cell_g(A.peF + (size_t)(b0 + bsub * 16) * 512, 512, Wpd[usub], acc, lane);
            else        cell_g(A.H1 + ((size_t)((t - 1) & 1) * BATCH + b0 + bsub * 16) * HID, HID,
                               Wpd[usub], acc, lane);
#pragma unroll
            for (int r = 0; r < 4; ++r) {
                const int bl = bsub * 16 + fq * 4 + r, b = b0 + bl;
                const float x0 = pred_lds[bl * 3 + 0];
                const float x1 = pred_lds[bl * 3 + 1];
                const float x2 = pred_lds[bl * 3 + 2];
                float gv[4];
#pragma unroll
                for (int g = 0; g < 4; ++g)
                    gv[g] = acc[g][r] + pdb[g] + x0 * wxs[g][0] + x1 * wxs[g][1] + x2 * wxs[g][2];
                const float cn = sigmf(gv[1]) * c1[r] + sigmf(gv[0]) * tanhf(gv[2]);
                const float hn = sigmf(gv[3]) * tanhf(cn);
                c1[r] = cn;
                A.H1[((size_t)(t & 1) * BATCH + b) * HID + u] = f2bf(hn);
            }
        }
        gbar(A.bar + btile * 2 * HWIN + 2 * t, 8);
        // ---- phase B: fd cell + tail partials ----
        {
            f32x4 acc[4] = {};
            cell_g(A.H1 + ((size_t)(t & 1) * BATCH + b0 + bsub * 16) * HID, HID,
                   Wfd[usub], acc, lane);
#pragma unroll
            for (int r = 0; r < 4; ++r) {
                const int b = b0 + bsub * 16 + fq * 4 + r;
                float gv[4];
#pragma unroll
                for (int g = 0; g < 4; ++g)
                    gv[g] = acc[g][r] + xh[r][g] + gb[r][g];
                const float cn = sigmf(gv[1]) * cf[r] + sigmf(gv[0]) * tanhf(gv[2]);
                const float hn = sigmf(gv[3]) * tanhf(cn);
                float p0 = hn * Gu[0], p1 = hn * Gu[1], p2 = hn * Gu[2];
#pragma unroll
                for (int s = 1; s < 16; s <<= 1) {
                    p0 += __shfl_xor(p0, s);
                    p1 += __shfl_xor(p1, s);
                    p2 += __shfl_xor(p2, s);
                }
                if (fr == 0) {
                    float* d = A.DELTA + ((size_t)t * 512 + b) * 3;
                    atomicAdd(d + 0, p0); atomicAdd(d + 1, p1); atomicAdd(d + 2, p2);
                }
            }
        }
        gbar(A.bar + btile * 2 * HWIN + 2 * t + 1, 8);
        // ---- pred update + out write ----
        if (tid < 192) {
            pred_lds[tid] += A.DELTA[((size_t)t * 512 + b0 + tid / 3) * 3 + tid % 3] + c3r;
            if (usup == 0)
                A.out[((size_t)(b0 + tid / 3) * HWIN + t) * 3 + tid % 3] = pred_lds[tid];
        }
        __syncthreads();
    }
}

// ---------------- G = out_W @ f2_W, c3 = out_b + out_W @ f2_b ----------------
__global__ __launch_bounds__(256)
void precompute_G(const float* __restrict__ f2W, const float* __restrict__ f2b,
                  const float* __restrict__ outW, const float* __restrict__ outb,
                  float* __restrict__ G, float* __restrict__ c3)
{
    const int k = threadIdx.x;
    float g0 = 0.f, g1 = 0.f, g2 = 0.f;
    for (int n = 0; n < HID; ++n) {
        const float w = f2W[n * HID + k];
        g0 += outW[n] * w;
        g1 += outW[HID + n] * w;
        g2 += outW[2 * HID + n] * w;
    }
    G[k] = g0; G[HID + k] = g1; G[2 * HID + k] = g2;
    if (k < 3) {
        float s = outb[k];
        for (int n = 0; n < HID; ++n) s += outW[k * HID + n] * f2b[n];
        c3[k] = s;
    }
}

extern "C" void kernel_launch(void* const* d_in, const int* in_sizes, int n_in,
                              void* d_out, int out_size, void* d_ws, size_t ws_size,
                              hipStream_t stream)
{
    (void)in_sizes; (void)n_in; (void)out_size; (void)ws_size;
    const float* enc_pos = (const float*)d_in[0];
    const float* enc_sal = (const float*)d_in[1];
    const float* dec_pos = (const float*)d_in[2];
    const float* dec_sal = (const float*)d_in[3];
    const float *pe_Wih = (const float*)d_in[4],  *pe_Whh = (const float*)d_in[5],
                *pe_bih = (const float*)d_in[6],  *pe_bhh = (const float*)d_in[7];
    const float *se_Wih = (const float*)d_in[8],  *se_Whh = (const float*)d_in[9],
                *se_bih = (const float*)d_in[10], *se_bhh = (const float*)d_in[11];
    const float *fe_Wih = (const float*)d_in[12], *fe_Whh = (const float*)d_in[13],
                *fe_bih = (const float*)d_in[14], *fe_bhh = (const float*)d_in[15];
    const float *pd_Wih = (const float*)d_in[16], *pd_Whh = (const float*)d_in[17],
                *pd_bih = (const float*)d_in[18], *pd_bhh = (const float*)d_in[19];
    const float *sd_Wih = (const float*)d_in[20], *sd_Whh = (const float*)d_in[21],
                *sd_bih = (const float*)d_in[22], *sd_bhh = (const float*)d_in[23];
    const float *fd_Wih = (const float*)d_in[24], *fd_Whh = (const float*)d_in[25],
                *fd_bih = (const float*)d_in[26], *fd_bhh = (const float*)d_in[27];
    const float *f2_W = (const float*)d_in[28], *f2_b = (const float*)d_in[29];
    const float *out_W = (const float*)d_in[30], *out_b = (const float*)d_in[31];
    float* out = (float*)d_out;
    float* ws  = (float*)d_ws;

    // ---- workspace (float units) ----
    size_t off = 0;
    float* XG_SE = ws + off; off += (size_t)8192 * 1024;    // se x-proj, rows (b,t)
    float* XG_FE = ws + off; off += (size_t)8192 * 1024;    // fe x-proj, rows (t,b)
    float* BIG   = ws + off; off += (size_t)12800 * 1024;   // sd x-proj, rows (b,t)
    float* BIG2  = ws + off; off += (size_t)12800 * 1024;   // fd Xh2, rows (t,b)
    float* GBIAS = ws + off; off += (size_t)BATCH * 1024;
    float* PE_C  = ws + off; off += BH;
    float* SE_C  = ws + off; off += BH;
    float* FE_C  = ws + off; off += BH;
    float* FEH   = ws + off; off += BH;
    float* Gm    = ws + off; off += 1024;
    float* C3    = ws + off; off += 8;
    float* DELTA = ws + off; off += (size_t)HWIN * BATCH * 3 + 64;
    unsigned int* BAR = (unsigned int*)(ws + off); off += 1280;
    ushort* ABUF = (ushort*)(ws + off); off += ((size_t)12800 * 4096) / 2;
    ushort* WSE  = (ushort*)(ws + off); off += ((size_t)1024 * 4096) / 2;
    ushort* WSD  = (ushort*)(ws + off); off += ((size_t)1024 * 4096) / 2;
    ushort* WFE  = (ushort*)(ws + off); off += ((size_t)1024 * 512) / 2;
    ushort* WFD  = (ushort*)(ws + off); off += ((size_t)1024 * 512) / 2;
    ushort* WHpe = (ushort*)(ws + off); off += ((size_t)1024 * 256) / 2;
    ushort* WHse = (ushort*)(ws + off); off += ((size_t)1024 * 256) / 2;
    ushort* WHfe = (ushort*)(ws + off); off += ((size_t)1024 * 256) / 2;
    ushort* WHsd = (ushort*)(ws + off); off += ((size_t)1024 * 256) / 2;
    ushort* WHpd = (ushort*)(ws + off); off += ((size_t)1024 * 256) / 2;
    ushort* CONC = (ushort*)(ws + off); off += ((size_t)MENC * 512 * 512) / 2;  // [t][b][512]
    ushort* SDB  = (ushort*)(ws + off); off += ((size_t)HWIN * BH) / 2;         // [t][b][256]
    ushort* FEB  = (ushort*)(ws + off); off += (size_t)BH;                      // [2][512][256]
    ushort* H1   = (ushort*)(ws + off); off += (size_t)BH;                      // [2][512][256]

    hipMemsetAsync(DELTA, 0, (size_t)HWIN * BATCH * 3 * 4, stream);
    hipMemsetAsync(BAR, 0, 1280 * 4, stream);

    auto cvt = [&](const float* in, ushort* outp, size_t n) {
        const int n4 = (int)(n / 4);
        cvt_f32_bf16<<<(n4 + 255) / 256, 256, 0, stream>>>(in, outp, n4);
    };
    auto mgemm = [&](const ushort* A, const ushort* W, float* C,
                     int M, int N, int K, int lda, int ldw, int ldc) {
        gemm_mfma_bt<<<dim3(N / 128, M / 128), 256, 0, stream>>>(A, W, C, M, N, K, lda, ldw, ldc);
    };

    // ---- one-time conversions / precomputes ----
    cvt(se_Wih, WSE, (size_t)1024 * SALSZ);
    cvt(sd_Wih, WSD, (size_t)1024 * SALSZ);
    cvt(fe_Wih, WFE, (size_t)1024 * 512);
    cvt(fd_Wih, WFD, (size_t)1024 * 512);
    cvt(pe_Whh, WHpe, (size_t)1024 * 256);
    cvt(se_Whh, WHse, (size_t)1024 * 256);
    cvt(fe_Whh, WHfe, (size_t)1024 * 256);
    cvt(sd_Whh, WHsd, (size_t)1024 * 256);
    cvt(pd_Whh, WHpd, (size_t)1024 * 256);
    cvt(enc_sal, ABUF, (size_t)8192 * SALSZ);
    precompute_G<<<1, 256, 0, stream>>>(f2_W, f2_b, out_W, out_b, Gm, C3);

    // ---- se x-projection ----
    mgemm(ABUF, WSE, XG_SE, 8192, 1024, SALSZ, SALSZ, SALSZ, 1024);

    // ---- persistent encoder (se + pe): 64 blocks x 1024 ----
    {
        EncArgs a;
        a.WHse = WHse; a.WHpe = WHpe; a.xg_se = XG_SE; a.enc_pos = enc_pos;
        a.se_b1 = se_bih; a.se_b2 = se_bhh; a.pe_b1 = pe_bih; a.pe_b2 = pe_bhh;
        a.pe_Wih = pe_Wih; a.conc = CONC; a.SE_C = SE_C; a.PE_C = PE_C;
        a.bar = BAR;
        enc_chain<<<64, 1024, 0, stream>>>(a);
    }

    // ---- fe x-proj (rows t,b) + sd x-proj ----
    mgemm(CONC, WFE, XG_FE, 8192, 1024, 512, 512, 512, 1024);
    cvt(dec_sal, ABUF, (size_t)12800 * SALSZ);
    mgemm(ABUF, WSD, BIG, 12800, 1024, SALSZ, SALSZ, SALSZ, 1024);

    // ---- persistent mid (sd + fe): 64 blocks x 1024 ----
    {
        MidArgs a;
        a.WHsd = WHsd; a.WHfe = WHfe; a.xg_sd = BIG; a.xg_fe = XG_FE;
        a.sd_b1 = sd_bih; a.sd_b2 = sd_bhh; a.fe_b1 = fe_bih; a.fe_b2 = fe_bhh;
        a.conc = CONC; a.SE_C = SE_C; a.SDB = SDB; a.FEB = FEB;
        a.FEH = FEH; a.FE_C = FE_C; a.bar = BAR + 256;
        mid_chain<<<64, 1024, 0, stream>>>(a);
    }

    // ---- fd precomputations ----
    mgemm(SDB, WFD, BIG2, 12800, 1024, HID, HID, 512, 1024);   // Xh2, rows (t,b)
    gemm_tn<<<dim3(16, 8), 256, 0, stream>>>(FEH, fd_Whh, fd_bih, fd_bhh, GBIAS,
                                             BATCH, 1024, HID, HID, HID, 1024);

    // ---- persistent decoder (pd + fd + tail): 64 blocks x 512 ----
    {
        DecArgs a;
        a.WHpd = WHpd; a.WFDh = WFD + 256;
        a.peF = CONC + ((size_t)15 * 512) * 512 + 256;
        a.PE_C = PE_C; a.FE_C = FE_C; a.GBIAS = GBIAS; a.xh2 = BIG2;
        a.pd_b1 = pd_bih; a.pd_b2 = pd_bhh; a.pd_Wih = pd_Wih;
        a.G = Gm; a.c3 = C3; a.dec_pos = dec_pos;
        a.H1 = H1; a.DELTA = DELTA; a.out = out; a.bar = BAR + 656;
        dec_chain<<<64, 512, 0, stream>>>(a);
    }
}